// Round 1
// 117.269 us; speedup vs baseline: 1.0296x; 1.0296x over previous
//
#include <hip/hip_runtime.h>
#include <math.h>

#define S_LEN 1024
#define D_DIM 64
#define NBH   16
#define RPB   14
#define NSB   74           // ceil(1024/14)

typedef unsigned short ushort_t;
typedef unsigned int uint_t;
typedef __attribute__((ext_vector_type(8))) _Float16 half8;  // 8 f16 (4 VGPRs)
typedef __attribute__((ext_vector_type(2))) _Float16 h2;
typedef __attribute__((ext_vector_type(4))) short short4v;   // 8 B
typedef __attribute__((ext_vector_type(4))) float f32x4;

__device__ __forceinline__ ushort_t f16bits(float x) {
    _Float16 h = (_Float16)x;                 // RNE
    ushort_t b;
    __builtin_memcpy(&b, &h, 2);
    return b;
}
__device__ __forceinline__ h2 as_h2(uint_t u) {
    h2 r;
    __builtin_memcpy(&r, &u, 4);
    return r;
}
__device__ __forceinline__ float uniform_f(float x) {
    // force a uniform value into an SGPR (saves VGPRs, enables sgpr operand)
    return __int_as_float(__builtin_amdgcn_readfirstlane(__float_as_int(x)));
}
__device__ __forceinline__ float fast_exp2(float x) {
#if __has_builtin(__builtin_amdgcn_exp2f)
    return __builtin_amdgcn_exp2f(x);         // v_exp_f32 (2^x)
#else
    return exp2f(x);
#endif
}

// ------------------------------ Prep ----------------------------------------
// blocks [0,512):    K * 0.125 -> f16 QK B-frag tiled layout (16B stores)
//                    (1/sqrt(D) folded into K so Phase A skips the scale)
// blocks [512,768):  V transpose -> f16 PV B-frag tiled layout
// blocks [768,1024): mask bit-pack, thread-per-word
__global__ __launch_bounds__(256) void prep(
    const float* __restrict__ k, const float* __restrict__ v,
    const int* __restrict__ mask,
    ushort_t* __restrict__ kh, ushort_t* __restrict__ vh,
    unsigned* __restrict__ mw)
{
    __shared__ float Ls[64][65];
    const int tid = threadIdx.x;
    const int bx = blockIdx.x;
    if (bx < 512) {
        const int gid  = bx * 256 + tid;          // 0..131071
        const int bh   = gid >> 13;
        const int tile = (gid >> 7) & 63;
        const int ch   = (gid >> 6) & 1;
        const int lane = gid & 63;
        const int quad = lane >> 4, t15 = lane & 15;
        const float* src = k + ((size_t)bh * S_LEN + tile * 16 + t15) * D_DIM
                             + ch * 32 + quad * 8;
        float x[8];
        *(float4*)(x + 0) = *(const float4*)(src);
        *(float4*)(x + 4) = *(const float4*)(src + 4);
        ushort_t hv[8];
        #pragma unroll
        for (int i = 0; i < 8; ++i) hv[i] = f16bits(x[i] * 0.125f);
        *(short4v*)(kh + (size_t)gid * 8)     = *(short4v*)(hv);
        *(short4v*)(kh + (size_t)gid * 8 + 4) = *(short4v*)(hv + 4);
    } else if (bx < 768) {
        const int bi = bx - 512;
        const int tt = bi & 15, bh = bi >> 4;
        const float* vb = v + ((size_t)bh * S_LEN + tt * 64) * D_DIM;
        #pragma unroll
        for (int p = 0; p < 4; ++p) {
            int idx = p * 1024 + tid * 4;
            int r = idx >> 6, c = idx & 63;
            float4 x = *(const float4*)(vb + r * 64 + c);
            Ls[r][c] = x.x; Ls[r][c+1] = x.y; Ls[r][c+2] = x.z; Ls[r][c+3] = x.w;
        }
        __syncthreads();
        const int d = tid >> 2, c0 = (tid & 3) * 16;
        ushort_t hi[16];
        #pragma unroll
        for (int j = 0; j < 16; ++j) hi[j] = f16bits(Ls[c0 + j][d]);
        const int tb0 = tt * 8 + (c0 >> 3);
        const size_t o0 = (((size_t)bh * 128 + tb0) * 64 + d) * 8;
        const size_t o1 = (((size_t)bh * 128 + tb0 + 1) * 64 + d) * 8;
        *(short4v*)(vh + o0)     = *(short4v*)(hi);
        *(short4v*)(vh + o0 + 4) = *(short4v*)(hi + 4);
        *(short4v*)(vh + o1)     = *(short4v*)(hi + 8);
        *(short4v*)(vh + o1 + 4) = *(short4v*)(hi + 12);
    } else {
        const int gid = (bx - 768) * 256 + tid;    // 0..65535
        const int row = gid >> 5, wd = gid & 31;   // row = b*1024+s
        const int4* mp = (const int4*)(mask + (size_t)row * 1024 + wd * 32);
        unsigned bits = 0;
        #pragma unroll
        for (int p = 0; p < 8; ++p) {
            int4 qv = mp[p];
            bits |= (qv.x != 0 ? 1u : 0u) << (p * 4 + 0);
            bits |= (qv.y != 0 ? 1u : 0u) << (p * 4 + 1);
            bits |= (qv.z != 0 ? 1u : 0u) << (p * 4 + 2);
            bits |= (qv.w != 0 ? 1u : 0u) << (p * 4 + 3);
        }
        mw[(size_t)row * 32 + wd] = bits;
    }
}

// ---------- Fused (RPB=14, f16, in-place P): QK^T -> conv -> PV --------------
// grid (74 s-tiles, 16 bh), block 512 = 8 waves. LDS ~38.8 KB.
// Phase A: 8 waves x 8 K-tiles; ONE 16-row f16 A-set (rows s0-1+m, K prescaled
//          by 1/8 in prep). dpH: col t at idx t+2, pads zeroed.
// Phase B: SCALAR conv core (v_pk_fma_f32 is half-rate on gfx950 -> packing
//          saves no VALU cycles and costs pair-build movs). Leaky-relu in
//          0.505x+0.495|x| form (|x| free via VOP3 abs modifier); log2(e)
//          folded into aF/bF/lb so exp is a bare v_exp_f32. Row-sum dropped
//          here entirely (no shfl chains) -- computed in Phase C by MFMA.
// Phase C: PV reads P from dpH; SECOND accumulator vs all-ones B fragment
//          gives row sums (16 extra MFMA on a 96%-idle pipe); th=0 partial
//          published via lsRow[16], th=1 waves add their own register copy.
#define DPSTR 1040  // dp/P row stride (halfs)
__global__ __launch_bounds__(512) void fused_qk_conv_av(
    const float* __restrict__ q,
    const ushort_t* __restrict__ kh, const unsigned* __restrict__ mw,
    const ushort_t* __restrict__ vh,
    const float* __restrict__ conv_w, const float* __restrict__ conv_b,
    const float* __restrict__ lin_w, const float* __restrict__ lin_b,
    float* __restrict__ out)
{
    __shared__ ushort_t dpH[16 * DPSTR];   // 33.3 KB; dp in A/B, P in C
    __shared__ float oBuf[16][68];         // 4.35 KB
    __shared__ float lsRow[16];            // 64 B (th=0 rowsum partials)
    __shared__ unsigned mb[16][32];        // 2 KB

    const int st = blockIdx.x, bh = blockIdx.y;
    const int s0 = st * RPB;
    const int b  = bh >> 3;
    const int tid = threadIdx.x;
    const int wave = tid >> 6, lane = tid & 63;
    const int m = lane & 15, quad = lane >> 4;

    // mask bits -> LDS (one word per thread; row o <-> s = s0-1+o)
    {
        const int o = tid >> 5, wd = tid & 31;
        const int s = s0 - 1 + o;
        mb[o][wd] = (s >= 0 && s < S_LEN)
                  ? mw[((size_t)b * S_LEN + s) * 32 + wd] : 0u;
    }
    // zero dpH pads: idx 0,1 (t=-2,-1) and 1026,1027 (t=1024,1025) per row
    if (tid < 64) {
        const int row = tid >> 2, i = tid & 3;
        const int idx = (i < 2) ? i : 1024 + i;
        dpH[row * DPSTR + idx] = 0;
    }

    // ---------------- Phase A: QK into LDS (single f16 A-set) ---------------
    const int sA = s0 - 1 + m;
    const int sQ = sA < 0 ? 0 : (sA > S_LEN - 1 ? S_LEN - 1 : sA);
    const float* qp = q + ((size_t)bh * S_LEN + sQ) * D_DIM + quad * 8;
    float qa[16];
    *(float4*)(qa + 0)  = *(const float4*)(qp + 0);
    *(float4*)(qa + 4)  = *(const float4*)(qp + 4);
    *(float4*)(qa + 8)  = *(const float4*)(qp + 32);
    *(float4*)(qa + 12) = *(const float4*)(qp + 36);
    half8 AH0, AH1;
    #pragma unroll
    for (int i = 0; i < 8; ++i) {
        AH0[i] = (_Float16)qa[i];          // 1/8 scale lives in kh now
        AH1[i] = (_Float16)qa[8 + i];
    }

    #pragma unroll
    for (int tt = 0; tt < 8; ++tt) {
        const int tile = wave * 8 + tt;
        const size_t kb = (((size_t)bh * 64 + tile) * 128 + lane) * 8;
        half8 KH0 = *(const half8*)(kh + kb);
        half8 KH1 = *(const half8*)(kh + kb + 512);
        f32x4 a = {0.f, 0.f, 0.f, 0.f};
        a = __builtin_amdgcn_mfma_f32_16x16x32_f16(AH0, KH0, a, 0, 0, 0);
        a = __builtin_amdgcn_mfma_f32_16x16x32_f16(AH1, KH1, a, 0, 0, 0);
        const int col = tile * 16 + m;
        #pragma unroll
        for (int r = 0; r < 4; ++r) {
            const int row = quad * 4 + r;
            const int s = s0 - 1 + row;
            const float v = (s >= 0 && s < S_LEN) ? a[r] : 0.f;
            dpH[row * DPSTR + col + 2] = f16bits(v);
        }
    }

    // hoisted uniform coefficients (SGPR via readfirstlane)
    float w[36];
    #pragma unroll
    for (int i = 0; i < 36; ++i) w[i] = conv_w[i];
    const float L2E = 1.44269504088896341f;
    float cb[4], aF[4], bF[4];
    #pragma unroll
    for (int f = 0; f < 4; ++f) {
        cb[f] = conv_b[f];
        const float lwf = lin_w[f];
        aF[f] = uniform_f(0.505f * lwf * L2E);   // lr(x)=0.505x+0.495|x|
        bF[f] = uniform_f(0.495f * lwf * L2E);
    }
    const float lbE = uniform_f(lin_b[0] * L2E);

    __syncthreads();

    // ---------------- Phase B: conv + mask + exp2 (P held in registers) -----
    const int rh = tid >> 8, cg = tid & 255, c0 = cg * 4;
    uint2 Ps[8];           // packed f16 P: [pass*4 + jo]
    #pragma unroll
    for (int pass = 0; pass < 2; ++pass) {
        const int obase = rh * 8 + pass * 4;        // first of 4 output rows
        float xv[6][6];                             // cols c0-1 .. c0+4
        #pragma unroll
        for (int jj = 0; jj < 6; ++jj) {
            const int dr = obase - 1 + jj;          // -1..16
            if (dr >= 0 && dr < 16) {
                const ushort_t* rp = &dpH[dr * DPSTR + c0];
                uint2 r0 = *(const uint2*)rp;        // t: c0-2,c0-1 | c0,c0+1
                uint2 r1 = *(const uint2*)(rp + 4);  // t: c0+2,c0+3 | c0+4,c0+5
                h2 pA = as_h2(r0.x), pB = as_h2(r0.y);
                h2 pC = as_h2(r1.x), pD = as_h2(r1.y);
                xv[jj][0] = (float)pA[1];
                xv[jj][1] = (float)pB[0]; xv[jj][2] = (float)pB[1];
                xv[jj][3] = (float)pC[0]; xv[jj][4] = (float)pC[1];
                xv[jj][5] = (float)pD[0];
            } else {
                #pragma unroll
                for (int i = 0; i < 6; ++i) xv[jj][i] = 0.f;
            }
        }
        #pragma unroll
        for (int jo = 0; jo < 4; ++jo) {
            const int o = obase + jo;               // wave-uniform guard
            const bool act = (o >= 1) && (o <= RPB) && (s0 - 1 + o < S_LEN);
            if (act) {
                float pr[4] = {lbE, lbE, lbE, lbE}; // pre-attn * log2(e)
                #pragma unroll
                for (int f = 0; f < 4; ++f) {
                    const float* wf = w + f * 9;
                    float acc[4];
                    const float w00 = wf[0];        // first tap: mul, no init
                    #pragma unroll
                    for (int c = 0; c < 4; ++c) acc[c] = w00 * xv[jo][c];
                    #pragma unroll
                    for (int t = 1; t < 9; ++t) {
                        const int dr = t / 3, dc = t % 3;
                        const float wt = wf[t];
                        #pragma unroll
                        for (int c = 0; c < 4; ++c)
                            acc[c] = fmaf(wt, xv[jo + dr][dc + c], acc[c]);
                    }
                    const float cbf = cb[f], af = aF[f], bf = bF[f];
                    #pragma unroll
                    for (int c = 0; c < 4; ++c) {
                        const float y = acc[c] + cbf;
                        pr[c] = fmaf(af, y, pr[c]);
                        pr[c] = fmaf(bf, fabsf(y), pr[c]);  // abs = modifier
                    }
                }
                const unsigned word = mb[o][cg >> 3];
                const unsigned nib  = (word >> ((cg & 7) * 4)) & 0xFu;
                float pv[4];
                #pragma unroll
                for (int c = 0; c < 4; ++c) {
                    const float pe = ((nib >> c) & 1u) ? pr[c] : -1e30f;
                    pv[c] = fast_exp2(pe);          // exp(pre) == 2^(pre*L2E)
                }
                Ps[pass * 4 + jo].x =
                    (uint_t)f16bits(pv[0]) | ((uint_t)f16bits(pv[1]) << 16);
                Ps[pass * 4 + jo].y =
                    (uint_t)f16bits(pv[2]) | ((uint_t)f16bits(pv[3]) << 16);
            } else {
                Ps[pass * 4 + jo].x = 0u;
                Ps[pass * 4 + jo].y = 0u;
            }
        }
    }
    __syncthreads();   // all dp reads done -> safe to overwrite dpH with P

    // write P in place over dpH (col t at idx t)
    #pragma unroll
    for (int i = 0; i < 8; ++i) {
        const int o = rh * 8 + i;
        *(uint2*)&dpH[o * DPSTR + c0] = Ps[i];
    }
    __syncthreads();

    // ---------------- Phase C: PV + MFMA row sums ---------------------------
    const int d0 = (wave & 3) * 16;
    const int th = wave >> 2;
    f32x4 O  = {0.f, 0.f, 0.f, 0.f};
    f32x4 RS = {0.f, 0.f, 0.f, 0.f};
    half8 ONE;
    #pragma unroll
    for (int i = 0; i < 8; ++i) ONE[i] = (_Float16)1.0f;
    const ushort_t* ph_base = &dpH[m * DPSTR + th * 512 + quad * 8];
    const ushort_t* vv_base = vh + ((size_t)bh * 65536
                                    + (size_t)(th * 64 + quad) * 512
                                    + (size_t)(d0 + m) * 8);
    #pragma unroll 4
    for (int i = 0; i < 16; ++i) {
        half8 ph = *(const half8*)(ph_base + i * 32);
        half8 vv = *(const half8*)(vv_base + (size_t)i * 2048);
        O  = __builtin_amdgcn_mfma_f32_16x16x32_f16(ph, vv, O, 0, 0, 0);
        RS = __builtin_amdgcn_mfma_f32_16x16x32_f16(ph, ONE, RS, 0, 0, 0);
    }
    if (wave < 4) {
        #pragma unroll
        for (int r = 0; r < 4; ++r) oBuf[quad * 4 + r][d0 + m] = O[r];
    }
    if (wave == 0 && m == 0) {   // lanes 0,16,32,48: publish th=0 partials
        #pragma unroll
        for (int r = 0; r < 4; ++r) lsRow[quad * 4 + r] = RS[r];
    }
    __syncthreads();
    if (wave >= 4) {
        #pragma unroll
        for (int r = 0; r < 4; ++r) {
            const int br = quad * 4 + r;
            const int s = s0 - 1 + br;
            if (br >= 1 && br <= RPB && s < S_LEN) {
                const float lsum = lsRow[br] + RS[r];
                out[((size_t)bh * S_LEN + s) * D_DIM + d0 + m] =
                    (O[r] + oBuf[br][d0 + m]) / lsum;
            }
        }
    }
}

extern "C" void kernel_launch(void* const* d_in, const int* in_sizes, int n_in,
                              void* d_out, int out_size, void* d_ws, size_t ws_size,
                              hipStream_t stream) {
    const float* q      = (const float*)d_in[0];
    const float* k      = (const float*)d_in[1];
    const float* v      = (const float*)d_in[2];
    const int*   mask   = (const int*)d_in[3];
    const float* conv_w = (const float*)d_in[4];
    const float* conv_b = (const float*)d_in[5];
    const float* lin_w  = (const float*)d_in[6];
    const float* lin_b  = (const float*)d_in[7];
    float* out = (float*)d_out;

    char* wsb = (char*)d_ws;
    const size_t MB = 1024 * 1024;
    ushort_t* kh = (ushort_t*)(wsb + 0 * MB);     // 2 MiB
    ushort_t* vh = (ushort_t*)(wsb + 2 * MB);     // 2 MiB
    unsigned* mw = (unsigned*)(wsb + 4 * MB);     // 256 KiB

    prep<<<dim3(1024), 256, 0, stream>>>(k, v, mask, kh, vh, mw);
    fused_qk_conv_av<<<dim3(NSB, NBH), 512, 0, stream>>>(
        q, kh, mw, vh, conv_w, conv_b, lin_w, lin_b, out);
}